// Round 2
// baseline (753.436 us; speedup 1.0000x reference)
//
#include <hip/hip_runtime.h>

#define DIM 128
#define CAP 256
#define RSQRT_HD 0.17677669529663687f

// ---------------- GEMM: out[n,o] = sum_i X[n,i]*W[o,i] + bias[o] (+ res[n,o]) ----------------
// W is row-major [128 out][128 in]. Block: 32 rows x 128 cols, 4x4 register tile.
__global__ __launch_bounds__(256) void gemm128(const float* __restrict__ X,
    const float* __restrict__ W, const float* __restrict__ bias,
    const float* __restrict__ res, float* __restrict__ out, int nrows)
{
    __shared__ float xs[32][129];
    __shared__ float wt[32][129];   // wt[i][o] for current k-tile
    int t = threadIdx.x;
    int row0 = blockIdx.x << 5;
    int rg = t >> 5;   // 0..7  -> rows rg, rg+8, rg+16, rg+24
    int cg = t & 31;   // 0..31 -> cols cg, cg+32, cg+64, cg+96
    float acc[4][4] = {{0.f}};

    for (int idx = t; idx < 32 * 128; idx += 256) {
        int r = idx >> 7, c = idx & 127;
        int gr = row0 + r;
        xs[r][c] = (gr < nrows) ? X[(size_t)gr * DIM + c] : 0.f;
    }
    for (int k0 = 0; k0 < 128; k0 += 32) {
        __syncthreads();
        for (int idx = t; idx < 32 * 128; idx += 256) {
            int o = idx >> 5, i = idx & 31;
            wt[i][o] = W[o * DIM + k0 + i];
        }
        __syncthreads();
#pragma unroll
        for (int i = 0; i < 32; ++i) {
            float a0 = xs[rg][k0 + i], a1 = xs[rg + 8][k0 + i];
            float a2 = xs[rg + 16][k0 + i], a3 = xs[rg + 24][k0 + i];
            float b0 = wt[i][cg], b1 = wt[i][cg + 32], b2 = wt[i][cg + 64], b3 = wt[i][cg + 96];
            acc[0][0] += a0 * b0; acc[0][1] += a0 * b1; acc[0][2] += a0 * b2; acc[0][3] += a0 * b3;
            acc[1][0] += a1 * b0; acc[1][1] += a1 * b1; acc[1][2] += a1 * b2; acc[1][3] += a1 * b3;
            acc[2][0] += a2 * b0; acc[2][1] += a2 * b1; acc[2][2] += a2 * b2; acc[2][3] += a2 * b3;
            acc[3][0] += a3 * b0; acc[3][1] += a3 * b1; acc[3][2] += a3 * b2; acc[3][3] += a3 * b3;
        }
    }
    float bv0 = bias[cg], bv1 = bias[cg + 32], bv2 = bias[cg + 64], bv3 = bias[cg + 96];
#pragma unroll
    for (int r = 0; r < 4; ++r) {
        int gr = row0 + rg + 8 * r;
        if (gr >= nrows) continue;
        size_t base = (size_t)gr * DIM;
        float v0 = acc[r][0] + bv0, v1 = acc[r][1] + bv1, v2 = acc[r][2] + bv2, v3 = acc[r][3] + bv3;
        if (res) {
            v0 += res[base + cg];      v1 += res[base + cg + 32];
            v2 += res[base + cg + 64]; v3 += res[base + cg + 96];
        }
        out[base + cg] = v0;      out[base + cg + 32] = v1;
        out[base + cg + 64] = v2; out[base + cg + 96] = v3;
    }
}

// ---------------- edge_index dtype detection (int64 vs int32) ----------------
__global__ void detect64(const int* __restrict__ e, int* __restrict__ flag, int E)
{
    __shared__ int nz;
    int t = threadIdx.x;
    if (t == 0) nz = 0;
    __syncthreads();
    int lim = (E < 4096) ? E : 4096;   // scan first 4096 int32 words
    int mynz = 0;
    for (int i = 2 * t + 1; i < lim; i += 512) mynz |= (e[i] != 0);
    if (mynz) atomicOr(&nz, 1);
    __syncthreads();
    if (t == 0) *flag = nz ? 0 : 1;    // all odd words zero => int64 data
}

__device__ __forceinline__ int load_idx(const int* p32, const long long* p64, int is64, int i)
{
    return is64 ? (int)p64[i] : p32[i];
}

// ---------------- CSR build ----------------
__global__ void hist_kernel(const int* __restrict__ row32, const long long* __restrict__ row64,
                            const int* __restrict__ flag, int* __restrict__ deg, int E)
{
    int e = blockIdx.x * blockDim.x + threadIdx.x;
    if (e < E) atomicAdd(&deg[load_idx(row32, row64, *flag, e)], 1);
}

__global__ __launch_bounds__(256) void scan1(const int* __restrict__ in, int* __restrict__ incl,
                                             int* __restrict__ bsums, int n)
{
    __shared__ int s[256];
    int t = threadIdx.x;
    int base = blockIdx.x * 1024 + t * 4;
    int v0 = (base + 0 < n) ? in[base + 0] : 0;
    int v1 = (base + 1 < n) ? in[base + 1] : 0;
    int v2 = (base + 2 < n) ? in[base + 2] : 0;
    int v3 = (base + 3 < n) ? in[base + 3] : 0;
    int sum = v0 + v1 + v2 + v3;
    s[t] = sum;
    __syncthreads();
    for (int off = 1; off < 256; off <<= 1) {
        int x = (t >= off) ? s[t - off] : 0;
        __syncthreads();
        s[t] += x;
        __syncthreads();
    }
    int excl = s[t] - sum;
    if (base + 0 < n) incl[base + 0] = excl + v0;
    if (base + 1 < n) incl[base + 1] = excl + v0 + v1;
    if (base + 2 < n) incl[base + 2] = excl + v0 + v1 + v2;
    if (base + 3 < n) incl[base + 3] = excl + sum;
    if (t == 255) bsums[blockIdx.x] = s[255];
}

__global__ void scan2(int* bsums, int nb)
{
    if (threadIdx.x == 0 && blockIdx.x == 0) {
        int run = 0;
        for (int i = 0; i < nb; ++i) { int v = bsums[i]; bsums[i] = run; run += v; }
    }
}

__global__ void scan3(const int* __restrict__ incl, const int* __restrict__ bofs,
                      int* __restrict__ rowptr, int n)
{
    int i = blockIdx.x * 256 + threadIdx.x;
    if (i == 0) rowptr[0] = 0;
    if (i < n) rowptr[i + 1] = incl[i] + bofs[i >> 10];
}

__global__ void scatter_kernel(const int* __restrict__ e32, const long long* __restrict__ e64,
                               const int* __restrict__ flag, const int* __restrict__ rowptr,
                               int* __restrict__ cursor, int* __restrict__ colidx,
                               int* __restrict__ eidb, int E)
{
    int e = blockIdx.x * blockDim.x + threadIdx.x;
    if (e < E) {
        int is64 = *flag;
        int r = load_idx(e32, e64, is64, e);
        int c = load_idx(e32 + E, e64 + E, is64, e);
        int pos = rowptr[r] + atomicAdd(&cursor[r], 1);
        colidx[pos] = c;
        eidb[pos] = e;
    }
}

// ---------------- per-destination-node attention ----------------
// block = 128 threads = 4 heads x 32 dims; one block per node.
__global__ __launch_bounds__(128) void attn_kernel(const float* __restrict__ Q,
    const float* __restrict__ K, const float* __restrict__ V,
    const int* __restrict__ rowptr, const int* __restrict__ colidx,
    const int* __restrict__ eidb, float* __restrict__ attended,
    float* __restrict__ avg_out)
{
    int n = blockIdx.x;
    int t = threadIdx.x;
    int h = t >> 5, d = t & 31;
    int s0 = rowptr[n];
    int deg = rowptr[n + 1] - s0;
    float qv = Q[(size_t)n * DIM + t];
    __shared__ float sc[CAP * 5];   // stride 5: conflict-free strided column access
    __shared__ int scol[CAP];
    __shared__ int sei[CAP];

    if (deg <= CAP) {
        for (int e = t; e < deg; e += 128) { scol[e] = colidx[s0 + e]; sei[e] = eidb[s0 + e]; }
        __syncthreads();
        for (int e = 0; e < deg; ++e) {
            float kv = K[(size_t)scol[e] * DIM + t];
            float p = qv * kv;
#pragma unroll
            for (int off = 16; off; off >>= 1) p += __shfl_xor(p, off, 32);
            if (d == 0) sc[e * 5 + h] = p * RSQRT_HD;
        }
        __syncthreads();
        float m = -INFINITY;
        for (int e = d; e < deg; e += 32) m = fmaxf(m, sc[e * 5 + h]);
#pragma unroll
        for (int off = 16; off; off >>= 1) m = fmaxf(m, __shfl_xor(m, off, 32));
        float ssum = 0.f;
        for (int e = d; e < deg; e += 32) ssum += __expf(sc[e * 5 + h] - m);
#pragma unroll
        for (int off = 16; off; off >>= 1) ssum += __shfl_xor(ssum, off, 32);
        float inv = 1.f / (ssum + 1e-16f);
        for (int e = d; e < deg; e += 32) sc[e * 5 + h] = __expf(sc[e * 5 + h] - m) * inv;
        __syncthreads();
        for (int e = t; e < deg; e += 128)
            avg_out[sei[e]] = 0.25f * (sc[e * 5] + sc[e * 5 + 1] + sc[e * 5 + 2] + sc[e * 5 + 3]);
        float acc = 0.f;
        for (int e = 0; e < deg; ++e)
            acc += sc[e * 5 + h] * V[(size_t)scol[e] * DIM + t];
        attended[(size_t)n * DIM + t] = acc;
    } else {
        // streaming fallback (degree > CAP; not expected for this dataset)
        float m = -INFINITY, ssum = 0.f;
        for (int e = 0; e < deg; ++e) {
            float kv = K[(size_t)colidx[s0 + e] * DIM + t];
            float p = qv * kv;
#pragma unroll
            for (int off = 16; off; off >>= 1) p += __shfl_xor(p, off, 32);
            p *= RSQRT_HD;
            float mn = fmaxf(m, p);
            ssum = ssum * __expf(m - mn) + __expf(p - mn);
            m = mn;
        }
        float inv = 1.f / (ssum + 1e-16f);
        float acc = 0.f;
        for (int e = 0; e < deg; ++e) {
            int c = colidx[s0 + e];
            float kv = K[(size_t)c * DIM + t];
            float p = qv * kv;
#pragma unroll
            for (int off = 16; off; off >>= 1) p += __shfl_xor(p, off, 32);
            float a = __expf(p * RSQRT_HD - m) * inv;
            if (d == 0) sc[h] = a;
            __syncthreads();
            if (t == 0) avg_out[eidb[s0 + e]] = 0.25f * (sc[0] + sc[1] + sc[2] + sc[3]);
            acc += a * V[(size_t)c * DIM + t];
            __syncthreads();
        }
        attended[(size_t)n * DIM + t] = acc;
    }
}

extern "C" void kernel_launch(void* const* d_in, const int* in_sizes, int n_in,
                              void* d_out, int out_size, void* d_ws, size_t ws_size,
                              hipStream_t stream)
{
    const float* x  = (const float*)d_in[0];
    const int* e32  = (const int*)d_in[1];
    const long long* e64 = (const long long*)d_in[1];
    const float* Wq = (const float*)d_in[2];
    const float* bq = (const float*)d_in[3];
    const float* Wk = (const float*)d_in[4];
    const float* bk = (const float*)d_in[5];
    const float* Wv = (const float*)d_in[6];
    const float* bv = (const float*)d_in[7];
    const float* Wo = (const float*)d_in[8];
    const float* bo = (const float*)d_in[9];

    int N = in_sizes[0] / DIM;
    int E = in_sizes[1] / 2;

    float* out = (float*)d_out;
    float* avg_out = out + (size_t)N * DIM;

    char* w = (char*)d_ws;
    auto carve = [&](size_t bytes) -> void* {
        void* p = (void*)w;
        w += (bytes + 255) & ~(size_t)255;
        return p;
    };
    float* Qb  = (float*)carve((size_t)N * DIM * 4);   // also reused as `attended`
    float* Kb  = (float*)carve((size_t)N * DIM * 4);
    float* Vb  = (float*)carve((size_t)N * DIM * 4);
    int* deg    = (int*)carve((size_t)N * 4);
    int* tmp    = (int*)carve((size_t)N * 4);
    int* rowptr = (int*)carve(((size_t)N + 1) * 4);
    int* cursor = (int*)carve((size_t)N * 4);
    int* bsums  = (int*)carve(512 * 4);
    int* flag   = (int*)carve(256);
    int* colidx = (int*)carve((size_t)E * 4);
    int* eidb   = (int*)carve((size_t)E * 4);

    hipMemsetAsync(deg, 0, (size_t)N * 4, stream);
    hipMemsetAsync(cursor, 0, (size_t)N * 4, stream);

    int gemmBlocks = (N + 31) / 32;
    gemm128<<<gemmBlocks, 256, 0, stream>>>(x, Wq, bq, nullptr, Qb, N);
    gemm128<<<gemmBlocks, 256, 0, stream>>>(x, Wk, bk, nullptr, Kb, N);
    gemm128<<<gemmBlocks, 256, 0, stream>>>(x, Wv, bv, nullptr, Vb, N);

    detect64<<<1, 256, 0, stream>>>(e32, flag, 2 * E);
    hist_kernel<<<(E + 255) / 256, 256, 0, stream>>>(e32, e64, flag, deg, E);
    int nb = (N + 1023) / 1024;
    scan1<<<nb, 256, 0, stream>>>(deg, tmp, bsums, N);
    scan2<<<1, 1, 0, stream>>>(bsums, nb);
    scan3<<<(N + 255) / 256, 256, 0, stream>>>(tmp, bsums, rowptr, N);
    scatter_kernel<<<(E + 255) / 256, 256, 0, stream>>>(e32, e64, flag, rowptr, cursor, colidx, eidb, E);

    attn_kernel<<<N, 128, 0, stream>>>(Qb, Kb, Vb, rowptr, colidx, eidb, Qb /*attended aliases Q*/, avg_out);

    gemm128<<<gemmBlocks, 256, 0, stream>>>(Qb, Wo, bo, x, out, N);
}

// Round 4
// 495.565 us; speedup vs baseline: 1.5204x; 1.5204x over previous
//
#include <hip/hip_runtime.h>
#include <hip/hip_bf16.h>

#define DIM 128
#define CAP 128
#define RSQRT_HD 0.17677669529663687f   // 1/sqrt(32)

typedef float f32x4 __attribute__((ext_vector_type(4)));
typedef short bf16x8 __attribute__((ext_vector_type(8)));

__device__ __forceinline__ float bf2f(unsigned short u) {
    unsigned int x = ((unsigned int)u) << 16;
    union { unsigned int i; float f; } c; c.i = x; return c.f;
}
__device__ __forceinline__ unsigned short f2bf(float f) {
    __hip_bfloat16 h = __float2bfloat16(f);
    unsigned short u;
    __builtin_memcpy(&u, &h, 2);
    return u;
}
__device__ __forceinline__ void wave_lds_fence() {
    asm volatile("s_waitcnt lgkmcnt(0)" ::: "memory");
    __builtin_amdgcn_sched_barrier(0);
}

// ---------------- fp32 -> bf16 casts ----------------
__global__ __launch_bounds__(256) void cast_bf16(const float* __restrict__ src,
    unsigned short* __restrict__ dst, int n8)
{
    int i = blockIdx.x * 256 + threadIdx.x;
    if (i >= n8) return;
    f32x4 v0 = ((const f32x4*)src)[2 * i];
    f32x4 v1 = ((const f32x4*)src)[2 * i + 1];
    bf16x8 o;
    o[0] = (short)f2bf(v0[0]); o[1] = (short)f2bf(v0[1]);
    o[2] = (short)f2bf(v0[2]); o[3] = (short)f2bf(v0[3]);
    o[4] = (short)f2bf(v1[0]); o[5] = (short)f2bf(v1[1]);
    o[6] = (short)f2bf(v1[2]); o[7] = (short)f2bf(v1[3]);
    ((bf16x8*)dst)[i] = o;
}

// 4 weights of 128x128 in one launch: grid (8, 4)
__global__ __launch_bounds__(256) void cast_w4(
    const float* __restrict__ a, const float* __restrict__ b,
    const float* __restrict__ c, const float* __restrict__ d,
    unsigned short* __restrict__ oa, unsigned short* __restrict__ ob,
    unsigned short* __restrict__ oc, unsigned short* __restrict__ od)
{
    int w = blockIdx.y;
    const float* s = (w == 0) ? a : (w == 1) ? b : (w == 2) ? c : d;
    unsigned short* o = (w == 0) ? oa : (w == 1) ? ob : (w == 2) ? oc : od;
    int i = blockIdx.x * 256 + threadIdx.x;   // 0..2047
    f32x4 v0 = ((const f32x4*)s)[2 * i];
    f32x4 v1 = ((const f32x4*)s)[2 * i + 1];
    bf16x8 ov;
    ov[0] = (short)f2bf(v0[0]); ov[1] = (short)f2bf(v0[1]);
    ov[2] = (short)f2bf(v0[2]); ov[3] = (short)f2bf(v0[3]);
    ov[4] = (short)f2bf(v1[0]); ov[5] = (short)f2bf(v1[1]);
    ov[6] = (short)f2bf(v1[2]); ov[7] = (short)f2bf(v1[3]);
    ((bf16x8*)o)[i] = ov;
}

// ---------------- MFMA GEMM: out[r,c] = sum_k A[r,k]*W[c,k] + bias[c] (+res) ----------------
// No LDS: A rows are used by exactly one block (N=128 fits one block-tile);
// W (32 KB bf16) is L1-resident. 256 thr = 4 waves, 32 rows/wave, full 128 cols.
__device__ __forceinline__ void gemm_body(const unsigned short* __restrict__ A,
    const unsigned short* __restrict__ W, const float* __restrict__ bias,
    const float* __restrict__ res, float* __restrict__ outf,
    unsigned short* __restrict__ outb, int M, int bx)
{
    int lane = threadIdx.x & 63;
    int wave = threadIdx.x >> 6;
    int row0 = bx * 128 + wave * 32;
    int r16 = lane & 15;
    int kg = lane >> 4;
    int koff = kg * 8;

    f32x4 acc[2][8] = {};
    int ra0 = row0 + r16;       if (ra0 > M - 1) ra0 = M - 1;
    int ra1 = row0 + 16 + r16;  if (ra1 > M - 1) ra1 = M - 1;
    const unsigned short* pa0 = A + (size_t)ra0 * DIM + koff;
    const unsigned short* pa1 = A + (size_t)ra1 * DIM + koff;
    const unsigned short* pw = W + r16 * DIM + koff;

#pragma unroll
    for (int k0 = 0; k0 < 128; k0 += 32) {
        bf16x8 a0 = *(const bf16x8*)(pa0 + k0);
        bf16x8 a1 = *(const bf16x8*)(pa1 + k0);
        bf16x8 bw[8];
#pragma unroll
        for (int ct = 0; ct < 8; ++ct)
            bw[ct] = *(const bf16x8*)(pw + ct * 16 * DIM + k0);
#pragma unroll
        for (int ct = 0; ct < 8; ++ct) {
            acc[0][ct] = __builtin_amdgcn_mfma_f32_16x16x32_bf16(a0, bw[ct], acc[0][ct], 0, 0, 0);
            acc[1][ct] = __builtin_amdgcn_mfma_f32_16x16x32_bf16(a1, bw[ct], acc[1][ct], 0, 0, 0);
        }
    }

    float biasv[8];
#pragma unroll
    for (int ct = 0; ct < 8; ++ct) biasv[ct] = bias[ct * 16 + r16];

#pragma unroll
    for (int rt = 0; rt < 2; ++rt) {
        int rbase = row0 + rt * 16 + kg * 4;
#pragma unroll
        for (int ct = 0; ct < 8; ++ct) {
            int c = ct * 16 + r16;
#pragma unroll
            for (int j = 0; j < 4; ++j) {
                int r = rbase + j;
                if (r < M) {
                    float val = acc[rt][ct][j] + biasv[ct];
                    if (outf) outf[(size_t)r * DIM + c] = val + res[(size_t)r * DIM + c];
                    else      outb[(size_t)r * DIM + c] = f2bf(val);
                }
            }
        }
    }
}

__global__ __launch_bounds__(256) void gemm_qkv(const unsigned short* __restrict__ X,
    const unsigned short* __restrict__ Wq, const unsigned short* __restrict__ Wk,
    const unsigned short* __restrict__ Wv,
    const float* __restrict__ bq, const float* __restrict__ bk, const float* __restrict__ bv,
    unsigned short* __restrict__ Q, unsigned short* __restrict__ K, unsigned short* __restrict__ V,
    int M)
{
    int y = blockIdx.y;
    const unsigned short* W = (y == 0) ? Wq : (y == 1) ? Wk : Wv;
    const float* bias        = (y == 0) ? bq : (y == 1) ? bk : bv;
    unsigned short* out      = (y == 0) ? Q  : (y == 1) ? K  : V;
    gemm_body(X, W, bias, nullptr, nullptr, out, M, blockIdx.x);
}

__global__ __launch_bounds__(256) void gemm_final(const unsigned short* __restrict__ A,
    const unsigned short* __restrict__ W, const float* __restrict__ bias,
    const float* __restrict__ res, float* __restrict__ out, int M)
{
    gemm_body(A, W, bias, res, out, nullptr, M, blockIdx.x);
}

// ---------------- edge_index dtype detection (int64 vs int32) ----------------
__global__ void detect64(const int* __restrict__ e, int* __restrict__ flag, int E)
{
    __shared__ int nz;
    int t = threadIdx.x;
    if (t == 0) nz = 0;
    __syncthreads();
    int lim = (E < 4096) ? E : 4096;
    int mynz = 0;
    for (int i = 2 * t + 1; i < lim; i += 512) mynz |= (e[i] != 0);
    if (mynz) atomicOr(&nz, 1);
    __syncthreads();
    if (t == 0) *flag = nz ? 0 : 1;
}

__device__ __forceinline__ int load_idx(const int* p32, const long long* p64, int is64, int i)
{
    return is64 ? (int)p64[i] : p32[i];
}

// ---------------- CSR build ----------------
__global__ void hist_kernel(const int* __restrict__ row32, const long long* __restrict__ row64,
                            const int* __restrict__ flag, int* __restrict__ deg, int E)
{
    int e = blockIdx.x * blockDim.x + threadIdx.x;
    if (e < E) atomicAdd(&deg[load_idx(row32, row64, *flag, e)], 1);
}

__global__ __launch_bounds__(256) void scan1(const int* __restrict__ in, int* __restrict__ incl,
                                             int* __restrict__ bsums, int n)
{
    __shared__ int s[256];
    int t = threadIdx.x;
    int base = blockIdx.x * 1024 + t * 4;
    int v0 = (base + 0 < n) ? in[base + 0] : 0;
    int v1 = (base + 1 < n) ? in[base + 1] : 0;
    int v2 = (base + 2 < n) ? in[base + 2] : 0;
    int v3 = (base + 3 < n) ? in[base + 3] : 0;
    int sum = v0 + v1 + v2 + v3;
    s[t] = sum;
    __syncthreads();
    for (int off = 1; off < 256; off <<= 1) {
        int x = (t >= off) ? s[t - off] : 0;
        __syncthreads();
        s[t] += x;
        __syncthreads();
    }
    int excl = s[t] - sum;
    if (base + 0 < n) incl[base + 0] = excl + v0;
    if (base + 1 < n) incl[base + 1] = excl + v0 + v1;
    if (base + 2 < n) incl[base + 2] = excl + v0 + v1 + v2;
    if (base + 3 < n) incl[base + 3] = excl + sum;
    if (t == 255) bsums[blockIdx.x] = s[255];
}

__global__ void scan2(int* bsums, int nb)
{
    if (threadIdx.x == 0 && blockIdx.x == 0) {
        int run = 0;
        for (int i = 0; i < nb; ++i) { int v = bsums[i]; bsums[i] = run; run += v; }
    }
}

__global__ void scan3(const int* __restrict__ incl, const int* __restrict__ bofs,
                      int* __restrict__ rowptr, int n)
{
    int i = blockIdx.x * 256 + threadIdx.x;
    if (i == 0) rowptr[0] = 0;
    if (i < n) rowptr[i + 1] = incl[i] + bofs[i >> 10];
}

__global__ void scatter_kernel(const int* __restrict__ e32, const long long* __restrict__ e64,
                               const int* __restrict__ flag, const int* __restrict__ rowptr,
                               int* __restrict__ cursor, int* __restrict__ colidx,
                               int* __restrict__ eidb, int E)
{
    int e = blockIdx.x * blockDim.x + threadIdx.x;
    if (e < E) {
        int is64 = *flag;
        int r = load_idx(e32, e64, is64, e);
        int c = load_idx(e32 + E, e64 + E, is64, e);
        int pos = rowptr[r] + atomicAdd(&cursor[r], 1);
        colidx[pos] = c;
        eidb[pos] = e;
    }
}

// ---------------- per-destination-node attention, one WAVE per node ----------------
// 256 thr = 4 waves = 4 nodes/block. lane l owns dims (2l, 2l+1); head h = l>>4.
// No block barriers: wave-synchronous LDS with explicit lgkmcnt fences.
__global__ __launch_bounds__(256) void attn_kernel(const unsigned short* __restrict__ Q,
    const unsigned short* __restrict__ K, const unsigned short* __restrict__ V,
    const int* __restrict__ rowptr, const int* __restrict__ colidx,
    const int* __restrict__ eidb, unsigned short* __restrict__ attended,
    float* __restrict__ avg_out, int N)
{
    __shared__ float sc_s[4][CAP * 5];
    __shared__ int scol_s[4][CAP];
    __shared__ int sei_s[4][CAP];

    int wave = threadIdx.x >> 6;
    int l = threadIdx.x & 63;
    int n = blockIdx.x * 4 + wave;
    bool active = n < N;
    int h = l >> 4;       // head
    int hl = l & 15;      // lane within head group
    float* sc = sc_s[wave];
    int* scol = scol_s[wave];
    int* sei = sei_s[wave];

    int s0 = active ? rowptr[n] : 0;
    int deg = active ? (rowptr[n + 1] - s0) : 0;

    float q0 = 0.f, q1 = 0.f;
    if (active) {
        ushort2 qq = *(const ushort2*)(Q + (size_t)n * DIM + 2 * l);
        q0 = bf2f(qq.x); q1 = bf2f(qq.y);
    }

    if (deg <= CAP) {
        for (int e = l; e < deg; e += 64) { scol[e] = colidx[s0 + e]; sei[e] = eidb[s0 + e]; }
        wave_lds_fence();
        for (int e = 0; e < deg; ++e) {
            int c = scol[e];
            ushort2 kk = *(const ushort2*)(K + (size_t)c * DIM + 2 * l);
            float p = q0 * bf2f(kk.x) + q1 * bf2f(kk.y);
#pragma unroll
            for (int off = 8; off; off >>= 1) p += __shfl_xor(p, off);
            if (hl == 0) sc[e * 5 + h] = p * RSQRT_HD;
        }
        wave_lds_fence();
        float m = -INFINITY;
        for (int e = hl; e < deg; e += 16) m = fmaxf(m, sc[e * 5 + h]);
#pragma unroll
        for (int off = 8; off; off >>= 1) m = fmaxf(m, __shfl_xor(m, off));
        float ssum = 0.f;
        for (int e = hl; e < deg; e += 16) ssum += __expf(sc[e * 5 + h] - m);
#pragma unroll
        for (int off = 8; off; off >>= 1) ssum += __shfl_xor(ssum, off);
        float inv = 1.f / (ssum + 1e-16f);
        for (int e = hl; e < deg; e += 16) sc[e * 5 + h] = __expf(sc[e * 5 + h] - m) * inv;
        wave_lds_fence();
        for (int e = l; e < deg; e += 64)
            avg_out[sei[e]] = 0.25f * (sc[e * 5] + sc[e * 5 + 1] + sc[e * 5 + 2] + sc[e * 5 + 3]);
        float a0 = 0.f, a1 = 0.f;
        for (int e = 0; e < deg; ++e) {
            float a = sc[e * 5 + h];
            ushort2 vv = *(const ushort2*)(V + (size_t)scol[e] * DIM + 2 * l);
            a0 += a * bf2f(vv.x);
            a1 += a * bf2f(vv.y);
        }
        if (active) {
            ushort2 o; o.x = f2bf(a0); o.y = f2bf(a1);
            *(ushort2*)(attended + (size_t)n * DIM + 2 * l) = o;
        }
    } else {
        // streaming two-pass fallback (deg > CAP; not expected for this dataset)
        float m = -INFINITY, ssum = 0.f;
        for (int e = 0; e < deg; ++e) {
            int c = colidx[s0 + e];
            ushort2 kk = *(const ushort2*)(K + (size_t)c * DIM + 2 * l);
            float p = q0 * bf2f(kk.x) + q1 * bf2f(kk.y);
#pragma unroll
            for (int off = 8; off; off >>= 1) p += __shfl_xor(p, off);
            p *= RSQRT_HD;
            float mn = fmaxf(m, p);
            ssum = ssum * __expf(m - mn) + __expf(p - mn);
            m = mn;
        }
        float inv = 1.f / (ssum + 1e-16f);
        float a0 = 0.f, a1 = 0.f;
        for (int e = 0; e < deg; ++e) {
            int c = colidx[s0 + e];
            ushort2 kk = *(const ushort2*)(K + (size_t)c * DIM + 2 * l);
            float p = q0 * bf2f(kk.x) + q1 * bf2f(kk.y);
#pragma unroll
            for (int off = 8; off; off >>= 1) p += __shfl_xor(p, off);
            float a = __expf(p * RSQRT_HD - m) * inv;
            float asum = a + __shfl_xor(a, 16);
            asum += __shfl_xor(asum, 32);
            if (l == 0) avg_out[eidb[s0 + e]] = 0.25f * asum;
            ushort2 vv = *(const ushort2*)(V + (size_t)c * DIM + 2 * l);
            a0 += a * bf2f(vv.x);
            a1 += a * bf2f(vv.y);
        }
        if (active) {
            ushort2 o; o.x = f2bf(a0); o.y = f2bf(a1);
            *(ushort2*)(attended + (size_t)n * DIM + 2 * l) = o;
        }
    }
}

extern "C" void kernel_launch(void* const* d_in, const int* in_sizes, int n_in,
                              void* d_out, int out_size, void* d_ws, size_t ws_size,
                              hipStream_t stream)
{
    const float* x  = (const float*)d_in[0];
    const int* e32  = (const int*)d_in[1];
    const long long* e64 = (const long long*)d_in[1];
    const float* Wq = (const float*)d_in[2];
    const float* bq = (const float*)d_in[3];
    const float* Wk = (const float*)d_in[4];
    const float* bk = (const float*)d_in[5];
    const float* Wv = (const float*)d_in[6];
    const float* bv = (const float*)d_in[7];
    const float* Wo = (const float*)d_in[8];
    const float* bo = (const float*)d_in[9];

    int N = in_sizes[0] / DIM;
    int E = in_sizes[1] / 2;

    float* out = (float*)d_out;
    float* avg_out = out + (size_t)N * DIM;

    char* w = (char*)d_ws;
    auto carve = [&](size_t bytes) -> void* {
        void* p = (void*)w;
        w += (bytes + 255) & ~(size_t)255;
        return p;
    };
    unsigned short* Xb = (unsigned short*)carve((size_t)N * DIM * 2);
    unsigned short* Qb = (unsigned short*)carve((size_t)N * DIM * 2);  // reused as `attended`
    unsigned short* Kb = (unsigned short*)carve((size_t)N * DIM * 2);
    unsigned short* Vb = (unsigned short*)carve((size_t)N * DIM * 2);
    unsigned short* Wqb = (unsigned short*)carve(DIM * DIM * 2);
    unsigned short* Wkb = (unsigned short*)carve(DIM * DIM * 2);
    unsigned short* Wvb = (unsigned short*)carve(DIM * DIM * 2);
    unsigned short* Wob = (unsigned short*)carve(DIM * DIM * 2);
    int* deg    = (int*)carve((size_t)N * 4);
    int* tmp    = (int*)carve((size_t)N * 4);
    int* rowptr = (int*)carve(((size_t)N + 1) * 4);
    int* cursor = (int*)carve((size_t)N * 4);
    int* bsums  = (int*)carve(512 * 4);
    int* flag   = (int*)carve(256);
    int* colidx = (int*)carve((size_t)E * 4);
    int* eidb   = (int*)carve((size_t)E * 4);

    hipMemsetAsync(deg, 0, (size_t)N * 4, stream);
    hipMemsetAsync(cursor, 0, (size_t)N * 4, stream);

    int n8 = N * DIM / 8;
    cast_bf16<<<(n8 + 255) / 256, 256, 0, stream>>>(x, Xb, n8);
    cast_w4<<<dim3(8, 4), 256, 0, stream>>>(Wq, Wk, Wv, Wo, Wqb, Wkb, Wvb, Wob);

    detect64<<<1, 256, 0, stream>>>(e32, flag, 2 * E);
    hist_kernel<<<(E + 255) / 256, 256, 0, stream>>>(e32, e64, flag, deg, E);
    int nb = (N + 1023) / 1024;
    scan1<<<nb, 256, 0, stream>>>(deg, tmp, bsums, N);
    scan2<<<1, 1, 0, stream>>>(bsums, nb);
    scan3<<<(N + 255) / 256, 256, 0, stream>>>(tmp, bsums, rowptr, N);
    scatter_kernel<<<(E + 255) / 256, 256, 0, stream>>>(e32, e64, flag, rowptr, cursor, colidx, eidb, E);

    int gx = (N + 127) / 128;
    gemm_qkv<<<dim3(gx, 3), 256, 0, stream>>>(Xb, Wqb, Wkb, Wvb, bq, bk, bv, Qb, Kb, Vb, N);

    attn_kernel<<<(N + 3) / 4, 256, 0, stream>>>(Qb, Kb, Vb, rowptr, colidx, eidb,
                                                 Qb /*attended aliases Q*/, avg_out, N);

    gemm_final<<<gx, 256, 0, stream>>>(Qb, Wob, bo, x, out, N);
}

// Round 7
// 426.210 us; speedup vs baseline: 1.7678x; 1.1627x over previous
//
#include <hip/hip_runtime.h>
#include <hip/hip_bf16.h>

#define DIM 128
#define CAP 64
#define RSQRT_HD 0.17677669529663687f   // 1/sqrt(32)

typedef float f32x4 __attribute__((ext_vector_type(4)));
typedef short bf16x8 __attribute__((ext_vector_type(8)));

__device__ __forceinline__ float bf2f(unsigned short u) {
    unsigned int x = ((unsigned int)u) << 16;
    union { unsigned int i; float f; } c; c.i = x; return c.f;
}
__device__ __forceinline__ unsigned short f2bf(float f) {
    __hip_bfloat16 h = __float2bfloat16(f);
    unsigned short u;
    __builtin_memcpy(&u, &h, 2);
    return u;
}
__device__ __forceinline__ void wave_lds_fence() {
    asm volatile("s_waitcnt lgkmcnt(0)" ::: "memory");
    __builtin_amdgcn_sched_barrier(0);
}

// ---------------- fp32 -> bf16 weight cast: 4 weights of 128x128, grid (8,4) ----------------
__global__ __launch_bounds__(256) void cast_w4(
    const float* __restrict__ a, const float* __restrict__ b,
    const float* __restrict__ c, const float* __restrict__ d,
    unsigned short* __restrict__ oa, unsigned short* __restrict__ ob,
    unsigned short* __restrict__ oc, unsigned short* __restrict__ od)
{
    int w = blockIdx.y;
    const float* s = (w == 0) ? a : (w == 1) ? b : (w == 2) ? c : d;
    unsigned short* o = (w == 0) ? oa : (w == 1) ? ob : (w == 2) ? oc : od;
    int i = blockIdx.x * 256 + threadIdx.x;   // 0..2047
    f32x4 v0 = ((const f32x4*)s)[2 * i];
    f32x4 v1 = ((const f32x4*)s)[2 * i + 1];
    bf16x8 ov;
    ov[0] = (short)f2bf(v0[0]); ov[1] = (short)f2bf(v0[1]);
    ov[2] = (short)f2bf(v0[2]); ov[3] = (short)f2bf(v0[3]);
    ov[4] = (short)f2bf(v1[0]); ov[5] = (short)f2bf(v1[1]);
    ov[6] = (short)f2bf(v1[2]); ov[7] = (short)f2bf(v1[3]);
    ((bf16x8*)o)[i] = ov;
}

// ---------------- MFMA GEMM: out[r,c] = sum_k A[r,k]*W[c,k] + bias[c] (+res) ----------------
// No LDS: A row-panel used by exactly one block; W (32 KB bf16) is L1/L2-resident.
// 256 thr = 4 waves, 32 rows/wave, full 128 cols. AF32: A is fp32 (convert in-reg).
template<bool AF32>
__device__ __forceinline__ void gemm_body(const void* __restrict__ Aptr,
    const unsigned short* __restrict__ W, const float* __restrict__ bias,
    const float* __restrict__ res, float* __restrict__ outf,
    unsigned short* __restrict__ outb, int M, int bx)
{
    int lane = threadIdx.x & 63;
    int wave = threadIdx.x >> 6;
    int row0 = bx * 128 + wave * 32;
    int r16 = lane & 15;
    int kg = lane >> 4;
    int koff = kg * 8;

    f32x4 acc[2][8] = {};
    int ra0 = row0 + r16;       if (ra0 > M - 1) ra0 = M - 1;
    int ra1 = row0 + 16 + r16;  if (ra1 > M - 1) ra1 = M - 1;

    const unsigned short* pa0b = AF32 ? nullptr : (const unsigned short*)Aptr + (size_t)ra0 * DIM + koff;
    const unsigned short* pa1b = AF32 ? nullptr : (const unsigned short*)Aptr + (size_t)ra1 * DIM + koff;
    const float* pa0f = AF32 ? (const float*)Aptr + (size_t)ra0 * DIM + koff : nullptr;
    const float* pa1f = AF32 ? (const float*)Aptr + (size_t)ra1 * DIM + koff : nullptr;
    const unsigned short* pw = W + r16 * DIM + koff;

#pragma unroll
    for (int k0 = 0; k0 < 128; k0 += 32) {
        bf16x8 a0, a1;
        if (AF32) {
            f32x4 lo0 = *(const f32x4*)(pa0f + k0), hi0 = *(const f32x4*)(pa0f + k0 + 4);
            f32x4 lo1 = *(const f32x4*)(pa1f + k0), hi1 = *(const f32x4*)(pa1f + k0 + 4);
#pragma unroll
            for (int j = 0; j < 4; ++j) {
                a0[j] = (short)f2bf(lo0[j]); a0[j + 4] = (short)f2bf(hi0[j]);
                a1[j] = (short)f2bf(lo1[j]); a1[j + 4] = (short)f2bf(hi1[j]);
            }
        } else {
            a0 = *(const bf16x8*)(pa0b + k0);
            a1 = *(const bf16x8*)(pa1b + k0);
        }
        bf16x8 bw[8];
#pragma unroll
        for (int ct = 0; ct < 8; ++ct)
            bw[ct] = *(const bf16x8*)(pw + ct * 16 * DIM + k0);
#pragma unroll
        for (int ct = 0; ct < 8; ++ct) {
            acc[0][ct] = __builtin_amdgcn_mfma_f32_16x16x32_bf16(a0, bw[ct], acc[0][ct], 0, 0, 0);
            acc[1][ct] = __builtin_amdgcn_mfma_f32_16x16x32_bf16(a1, bw[ct], acc[1][ct], 0, 0, 0);
        }
    }

    float biasv[8];
#pragma unroll
    for (int ct = 0; ct < 8; ++ct) biasv[ct] = bias[ct * 16 + r16];

#pragma unroll
    for (int rt = 0; rt < 2; ++rt) {
        int rbase = row0 + rt * 16 + kg * 4;
#pragma unroll
        for (int ct = 0; ct < 8; ++ct) {
            int c = ct * 16 + r16;
#pragma unroll
            for (int j = 0; j < 4; ++j) {
                int r = rbase + j;
                if (r < M) {
                    float val = acc[rt][ct][j] + biasv[ct];
                    if (outf) outf[(size_t)r * DIM + c] = val + res[(size_t)r * DIM + c];
                    else      outb[(size_t)r * DIM + c] = f2bf(val);
                }
            }
        }
    }
}

__global__ __launch_bounds__(256) void gemm_qkv(const float* __restrict__ X,
    const unsigned short* __restrict__ Wq, const unsigned short* __restrict__ Wk,
    const unsigned short* __restrict__ Wv,
    const float* __restrict__ bq, const float* __restrict__ bk, const float* __restrict__ bv,
    unsigned short* __restrict__ Q, unsigned short* __restrict__ K, unsigned short* __restrict__ V,
    int M)
{
    int y = blockIdx.y;
    const unsigned short* W = (y == 0) ? Wq : (y == 1) ? Wk : Wv;
    const float* bias        = (y == 0) ? bq : (y == 1) ? bk : bv;
    unsigned short* out      = (y == 0) ? Q  : (y == 1) ? K  : V;
    gemm_body<true>(X, W, bias, nullptr, nullptr, out, M, blockIdx.x);
}

__global__ __launch_bounds__(256) void gemm_final(const unsigned short* __restrict__ A,
    const unsigned short* __restrict__ W, const float* __restrict__ bias,
    const float* __restrict__ res, float* __restrict__ out, int M)
{
    gemm_body<false>(A, W, bias, res, out, nullptr, M, blockIdx.x);
}

// ---------------- edge_index dtype detection (int64 vs int32) ----------------
__global__ void detect64(const int* __restrict__ e, int* __restrict__ flag, int E)
{
    __shared__ int nz;
    int t = threadIdx.x;
    if (t == 0) nz = 0;
    __syncthreads();
    int lim = (E < 4096) ? E : 4096;
    int mynz = 0;
    for (int i = 2 * t + 1; i < lim; i += 512) mynz |= (e[i] != 0);
    if (mynz) atomicOr(&nz, 1);
    __syncthreads();
    if (t == 0) *flag = nz ? 0 : 1;
}

__device__ __forceinline__ int load_idx(const int* p32, const long long* p64, int is64, int i)
{
    return is64 ? (int)p64[i] : p32[i];
}

// ---------------- CSR build ----------------
__global__ void hist_kernel(const int* __restrict__ row32, const long long* __restrict__ row64,
                            const int* __restrict__ flag, int* __restrict__ deg, int E)
{
    int e = blockIdx.x * blockDim.x + threadIdx.x;
    if (e < E) atomicAdd(&deg[load_idx(row32, row64, *flag, e)], 1);
}

__global__ __launch_bounds__(256) void scan1(const int* __restrict__ in, int* __restrict__ incl,
                                             int* __restrict__ bsums, int n)
{
    __shared__ int s[256];
    int t = threadIdx.x;
    int base = blockIdx.x * 1024 + t * 4;
    int v0 = (base + 0 < n) ? in[base + 0] : 0;
    int v1 = (base + 1 < n) ? in[base + 1] : 0;
    int v2 = (base + 2 < n) ? in[base + 2] : 0;
    int v3 = (base + 3 < n) ? in[base + 3] : 0;
    int sum = v0 + v1 + v2 + v3;
    s[t] = sum;
    __syncthreads();
    for (int off = 1; off < 256; off <<= 1) {
        int x = (t >= off) ? s[t - off] : 0;
        __syncthreads();
        s[t] += x;
        __syncthreads();
    }
    int excl = s[t] - sum;
    if (base + 0 < n) incl[base + 0] = excl + v0;
    if (base + 1 < n) incl[base + 1] = excl + v0 + v1;
    if (base + 2 < n) incl[base + 2] = excl + v0 + v1 + v2;
    if (base + 3 < n) incl[base + 3] = excl + sum;
    if (t == 255) bsums[blockIdx.x] = s[255];
}

// parallel exclusive scan of bsums (nb <= 512), one block of 256
__global__ __launch_bounds__(256) void scan2(int* bsums, int nb)
{
    __shared__ int s[512];
    int t = threadIdx.x;
    s[t] = (t < nb) ? bsums[t] : 0;
    s[t + 256] = (t + 256 < nb) ? bsums[t + 256] : 0;
    __syncthreads();
    for (int off = 1; off < 512; off <<= 1) {
        int x0 = (t >= off) ? s[t - off] : 0;
        int i1 = t + 256;
        int x1 = (i1 >= off) ? s[i1 - off] : 0;
        __syncthreads();
        s[t] += x0;
        s[i1] += x1;
        __syncthreads();
    }
    // exclusive from inclusive
    if (t < nb) bsums[t] = (t == 0) ? 0 : s[t - 1];
    if (t + 256 < nb) bsums[t + 256] = s[t + 255];
}

__global__ void scan3(const int* __restrict__ incl, const int* __restrict__ bofs,
                      int* __restrict__ rowptr, int n)
{
    int i = blockIdx.x * 256 + threadIdx.x;
    if (i == 0) rowptr[0] = 0;
    if (i < n) rowptr[i + 1] = incl[i] + bofs[i >> 10];
}

__global__ void scatter_kernel(const int* __restrict__ e32, const long long* __restrict__ e64,
                               const int* __restrict__ flag, const int* __restrict__ rowptr,
                               int* __restrict__ cursor, int* __restrict__ colidx,
                               int* __restrict__ eidb, int E)
{
    int e = blockIdx.x * blockDim.x + threadIdx.x;
    if (e < E) {
        int is64 = *flag;
        int r = load_idx(e32, e64, is64, e);
        int c = load_idx(e32 + E, e64 + E, is64, e);
        int pos = rowptr[r] + atomicAdd(&cursor[r], 1);
        colidx[pos] = c;
        eidb[pos] = e;
    }
}

// ---------------- per-destination-node attention, one WAVE per node ----------------
// 256 thr = 4 waves = 4 nodes/block. lane l owns dims (2l, 2l+1); head h = l>>4.
// Wave-synchronous LDS (lgkmcnt fences, rule #18). Score/PV loops are 4-wide
// chunked: 4 independent row gathers in flight + 4 interleaved shfl chains (ILP
// vs the latency-bound serial loop measured in round 4).
__global__ __launch_bounds__(256) void attn_kernel(const unsigned short* __restrict__ Q,
    const unsigned short* __restrict__ K, const unsigned short* __restrict__ V,
    const int* __restrict__ rowptr, const int* __restrict__ colidx,
    const int* __restrict__ eidb, unsigned short* __restrict__ attended,
    float* __restrict__ avg_out, int N)
{
    __shared__ float sc_s[4][CAP * 5];
    __shared__ int scol_s[4][CAP];
    __shared__ int sei_s[4][CAP];

    int wave = threadIdx.x >> 6;
    int l = threadIdx.x & 63;
    int n = blockIdx.x * 4 + wave;
    bool active = n < N;
    int h = l >> 4;       // head
    int hl = l & 15;      // lane within head group
    float* sc = sc_s[wave];
    int* scol = scol_s[wave];
    int* sei = sei_s[wave];

    int s0 = active ? rowptr[n] : 0;
    int deg = active ? (rowptr[n + 1] - s0) : 0;

    float q0 = 0.f, q1 = 0.f;
    if (active) {
        ushort2 qq = *(const ushort2*)(Q + (size_t)n * DIM + 2 * l);
        q0 = bf2f(qq.x); q1 = bf2f(qq.y);
    }

    if (deg <= CAP) {
        for (int e = l; e < deg; e += 64) { scol[e] = colidx[s0 + e]; sei[e] = eidb[s0 + e]; }
        wave_lds_fence();
        int e = 0;
        for (; e + 4 <= deg; e += 4) {
            int c0 = scol[e], c1 = scol[e + 1], c2 = scol[e + 2], c3 = scol[e + 3];
            ushort2 k0v = *(const ushort2*)(K + (size_t)c0 * DIM + 2 * l);
            ushort2 k1v = *(const ushort2*)(K + (size_t)c1 * DIM + 2 * l);
            ushort2 k2v = *(const ushort2*)(K + (size_t)c2 * DIM + 2 * l);
            ushort2 k3v = *(const ushort2*)(K + (size_t)c3 * DIM + 2 * l);
            float p0 = q0 * bf2f(k0v.x) + q1 * bf2f(k0v.y);
            float p1 = q0 * bf2f(k1v.x) + q1 * bf2f(k1v.y);
            float p2 = q0 * bf2f(k2v.x) + q1 * bf2f(k2v.y);
            float p3 = q0 * bf2f(k3v.x) + q1 * bf2f(k3v.y);
#pragma unroll
            for (int off = 8; off; off >>= 1) {
                p0 += __shfl_xor(p0, off); p1 += __shfl_xor(p1, off);
                p2 += __shfl_xor(p2, off); p3 += __shfl_xor(p3, off);
            }
            if (hl == 0) {
                sc[(e + 0) * 5 + h] = p0 * RSQRT_HD;
                sc[(e + 1) * 5 + h] = p1 * RSQRT_HD;
                sc[(e + 2) * 5 + h] = p2 * RSQRT_HD;
                sc[(e + 3) * 5 + h] = p3 * RSQRT_HD;
            }
        }
        for (; e < deg; ++e) {
            int c = scol[e];
            ushort2 kk = *(const ushort2*)(K + (size_t)c * DIM + 2 * l);
            float p = q0 * bf2f(kk.x) + q1 * bf2f(kk.y);
#pragma unroll
            for (int off = 8; off; off >>= 1) p += __shfl_xor(p, off);
            if (hl == 0) sc[e * 5 + h] = p * RSQRT_HD;
        }
        wave_lds_fence();
        float m = -INFINITY;
        for (int e2 = hl; e2 < deg; e2 += 16) m = fmaxf(m, sc[e2 * 5 + h]);
#pragma unroll
        for (int off = 8; off; off >>= 1) m = fmaxf(m, __shfl_xor(m, off));
        float ssum = 0.f;
        for (int e2 = hl; e2 < deg; e2 += 16) ssum += __expf(sc[e2 * 5 + h] - m);
#pragma unroll
        for (int off = 8; off; off >>= 1) ssum += __shfl_xor(ssum, off);
        float inv = 1.f / (ssum + 1e-16f);
        for (int e2 = hl; e2 < deg; e2 += 16) sc[e2 * 5 + h] = __expf(sc[e2 * 5 + h] - m) * inv;
        wave_lds_fence();
        for (int e2 = l; e2 < deg; e2 += 64)
            avg_out[sei[e2]] = 0.25f * (sc[e2 * 5] + sc[e2 * 5 + 1] + sc[e2 * 5 + 2] + sc[e2 * 5 + 3]);
        float a0 = 0.f, a1 = 0.f;
        int e3 = 0;
        for (; e3 + 4 <= deg; e3 += 4) {
            int c0 = scol[e3], c1 = scol[e3 + 1], c2 = scol[e3 + 2], c3 = scol[e3 + 3];
            float w0 = sc[(e3 + 0) * 5 + h];
            float w1 = sc[(e3 + 1) * 5 + h];
            float w2 = sc[(e3 + 2) * 5 + h];
            float w3 = sc[(e3 + 3) * 5 + h];
            ushort2 v0 = *(const ushort2*)(V + (size_t)c0 * DIM + 2 * l);
            ushort2 v1 = *(const ushort2*)(V + (size_t)c1 * DIM + 2 * l);
            ushort2 v2 = *(const ushort2*)(V + (size_t)c2 * DIM + 2 * l);
            ushort2 v3 = *(const ushort2*)(V + (size_t)c3 * DIM + 2 * l);
            a0 += w0 * bf2f(v0.x); a1 += w0 * bf2f(v0.y);
            a0 += w1 * bf2f(v1.x); a1 += w1 * bf2f(v1.y);
            a0 += w2 * bf2f(v2.x); a1 += w2 * bf2f(v2.y);
            a0 += w3 * bf2f(v3.x); a1 += w3 * bf2f(v3.y);
        }
        for (; e3 < deg; ++e3) {
            float a = sc[e3 * 5 + h];
            ushort2 vv = *(const ushort2*)(V + (size_t)scol[e3] * DIM + 2 * l);
            a0 += a * bf2f(vv.x);
            a1 += a * bf2f(vv.y);
        }
        if (active) {
            ushort2 o; o.x = f2bf(a0); o.y = f2bf(a1);
            *(ushort2*)(attended + (size_t)n * DIM + 2 * l) = o;
        }
    } else {
        // streaming two-pass fallback (deg > CAP; correct for any degree)
        float m = -INFINITY, ssum = 0.f;
        for (int e = 0; e < deg; ++e) {
            int c = colidx[s0 + e];
            ushort2 kk = *(const ushort2*)(K + (size_t)c * DIM + 2 * l);
            float p = q0 * bf2f(kk.x) + q1 * bf2f(kk.y);
#pragma unroll
            for (int off = 8; off; off >>= 1) p += __shfl_xor(p, off);
            p *= RSQRT_HD;
            float mn = fmaxf(m, p);
            ssum = ssum * __expf(m - mn) + __expf(p - mn);
            m = mn;
        }
        float inv = 1.f / (ssum + 1e-16f);
        float a0 = 0.f, a1 = 0.f;
        for (int e = 0; e < deg; ++e) {
            int c = colidx[s0 + e];
            ushort2 kk = *(const ushort2*)(K + (size_t)c * DIM + 2 * l);
            float p = q0 * bf2f(kk.x) + q1 * bf2f(kk.y);
#pragma unroll
            for (int off = 8; off; off >>= 1) p += __shfl_xor(p, off);
            float a = __expf(p * RSQRT_HD - m) * inv;
            float asum = a + __shfl_xor(a, 16);
            asum += __shfl_xor(asum, 32);
            if (l == 0) avg_out[eidb[s0 + e]] = 0.25f * asum;
            ushort2 vv = *(const ushort2*)(V + (size_t)c * DIM + 2 * l);
            a0 += a * bf2f(vv.x);
            a1 += a * bf2f(vv.y);
        }
        if (active) {
            ushort2 o; o.x = f2bf(a0); o.y = f2bf(a1);
            *(ushort2*)(attended + (size_t)n * DIM + 2 * l) = o;
        }
    }
}

extern "C" void kernel_launch(void* const* d_in, const int* in_sizes, int n_in,
                              void* d_out, int out_size, void* d_ws, size_t ws_size,
                              hipStream_t stream)
{
    const float* x  = (const float*)d_in[0];
    const int* e32  = (const int*)d_in[1];
    const long long* e64 = (const long long*)d_in[1];
    const float* Wq = (const float*)d_in[2];
    const float* bq = (const float*)d_in[3];
    const float* Wk = (const float*)d_in[4];
    const float* bk = (const float*)d_in[5];
    const float* Wv = (const float*)d_in[6];
    const float* bv = (const float*)d_in[7];
    const float* Wo = (const float*)d_in[8];
    const float* bo = (const float*)d_in[9];

    int N = in_sizes[0] / DIM;
    int E = in_sizes[1] / 2;

    float* out = (float*)d_out;
    float* avg_out = out + (size_t)N * DIM;

    char* w = (char*)d_ws;
    auto carve = [&](size_t bytes) -> void* {
        void* p = (void*)w;
        w += (bytes + 255) & ~(size_t)255;
        return p;
    };
    unsigned short* Qb = (unsigned short*)carve((size_t)N * DIM * 2);  // reused as `attended`
    unsigned short* Kb = (unsigned short*)carve((size_t)N * DIM * 2);
    unsigned short* Vb = (unsigned short*)carve((size_t)N * DIM * 2);
    unsigned short* Wqb = (unsigned short*)carve(DIM * DIM * 2);
    unsigned short* Wkb = (unsigned short*)carve(DIM * DIM * 2);
    unsigned short* Wvb = (unsigned short*)carve(DIM * DIM * 2);
    unsigned short* Wob = (unsigned short*)carve(DIM * DIM * 2);
    int* deg    = (int*)carve((size_t)N * 4);
    int* tmp    = (int*)carve((size_t)N * 4);
    int* rowptr = (int*)carve(((size_t)N + 1) * 4);
    int* cursor = (int*)carve((size_t)N * 4);
    int* bsums  = (int*)carve(512 * 4);
    int* flag   = (int*)carve(256);
    int* colidx = (int*)carve((size_t)E * 4);
    int* eidb   = (int*)carve((size_t)E * 4);

    hipMemsetAsync(deg, 0, (size_t)N * 4, stream);
    hipMemsetAsync(cursor, 0, (size_t)N * 4, stream);

    cast_w4<<<dim3(8, 4), 256, 0, stream>>>(Wq, Wk, Wv, Wo, Wqb, Wkb, Wvb, Wob);

    detect64<<<1, 256, 0, stream>>>(e32, flag, 2 * E);
    hist_kernel<<<(E + 255) / 256, 256, 0, stream>>>(e32, e64, flag, deg, E);
    int nb = (N + 1023) / 1024;
    scan1<<<nb, 256, 0, stream>>>(deg, tmp, bsums, N);
    scan2<<<1, 256, 0, stream>>>(bsums, nb);
    scan3<<<(N + 255) / 256, 256, 0, stream>>>(tmp, bsums, rowptr, N);
    scatter_kernel<<<(E + 255) / 256, 256, 0, stream>>>(e32, e64, flag, rowptr, cursor, colidx, eidb, E);

    int gx = (N + 127) / 128;
    gemm_qkv<<<dim3(gx, 3), 256, 0, stream>>>(x, Wqb, Wkb, Wvb, bq, bk, bv, Qb, Kb, Vb, N);

    attn_kernel<<<(N + 3) / 4, 256, 0, stream>>>(Qb, Kb, Vb, rowptr, colidx, eidb,
                                                 Qb /*attended aliases Q*/, avg_out, N);

    gemm_final<<<gx, 256, 0, stream>>>(Qb, Wob, bo, x, out, N);
}

// Round 8
// 401.114 us; speedup vs baseline: 1.8784x; 1.0626x over previous
//
#include <hip/hip_runtime.h>
#include <hip/hip_bf16.h>

#define DIM 128
#define CAP 64
#define RSQRT_HD 0.17677669529663687f   // 1/sqrt(32)

typedef float f32x4 __attribute__((ext_vector_type(4)));
typedef short bf16x8 __attribute__((ext_vector_type(8)));

__device__ __forceinline__ float bf2f(unsigned short u) {
    unsigned int x = ((unsigned int)u) << 16;
    union { unsigned int i; float f; } c; c.i = x; return c.f;
}
__device__ __forceinline__ unsigned short f2bf(float f) {
    __hip_bfloat16 h = __float2bfloat16(f);
    unsigned short u;
    __builtin_memcpy(&u, &h, 2);
    return u;
}
__device__ __forceinline__ void wave_lds_fence() {
    asm volatile("s_waitcnt lgkmcnt(0)" ::: "memory");
    __builtin_amdgcn_sched_barrier(0);
}

// ---------------- fp32 -> bf16 weight cast: 4 weights of 128x128, grid (8,4) ----------------
__global__ __launch_bounds__(256) void cast_w4(
    const float* __restrict__ a, const float* __restrict__ b,
    const float* __restrict__ c, const float* __restrict__ d,
    unsigned short* __restrict__ oa, unsigned short* __restrict__ ob,
    unsigned short* __restrict__ oc, unsigned short* __restrict__ od)
{
    int w = blockIdx.y;
    const float* s = (w == 0) ? a : (w == 1) ? b : (w == 2) ? c : d;
    unsigned short* o = (w == 0) ? oa : (w == 1) ? ob : (w == 2) ? oc : od;
    int i = blockIdx.x * 256 + threadIdx.x;   // 0..2047
    f32x4 v0 = ((const f32x4*)s)[2 * i];
    f32x4 v1 = ((const f32x4*)s)[2 * i + 1];
    bf16x8 ov;
    ov[0] = (short)f2bf(v0[0]); ov[1] = (short)f2bf(v0[1]);
    ov[2] = (short)f2bf(v0[2]); ov[3] = (short)f2bf(v0[3]);
    ov[4] = (short)f2bf(v1[0]); ov[5] = (short)f2bf(v1[1]);
    ov[6] = (short)f2bf(v1[2]); ov[7] = (short)f2bf(v1[3]);
    ((bf16x8*)o)[i] = ov;
}

// ---------------- fused QKV MFMA GEMM: reads X once, computes Q,K,V ----------------
// 256 thr = 4 waves; wave owns 32 rows x 128 cols. X panel staged in registers
// as bf16 fragments (read ONCE, vs 3x in the unfused version). W bf16 tiles are
// L1/L2-resident. C/D layout per m89: col=lane&15, row=(lane>>4)*4+j.
__global__ __launch_bounds__(256) void gemm_qkv_fused(const float* __restrict__ X,
    const unsigned short* __restrict__ Wq, const unsigned short* __restrict__ Wk,
    const unsigned short* __restrict__ Wv,
    const float* __restrict__ bq, const float* __restrict__ bk, const float* __restrict__ bv,
    unsigned short* __restrict__ Q, unsigned short* __restrict__ K, unsigned short* __restrict__ V,
    int M)
{
    int lane = threadIdx.x & 63;
    int wave = threadIdx.x >> 6;
    int row0 = blockIdx.x * 128 + wave * 32;
    int r16 = lane & 15;
    int kg = lane >> 4;
    int koff = kg * 8;

    int ra0 = row0 + r16;       if (ra0 > M - 1) ra0 = M - 1;
    int ra1 = row0 + 16 + r16;  if (ra1 > M - 1) ra1 = M - 1;
    const float* pa0f = X + (size_t)ra0 * DIM + koff;
    const float* pa1f = X + (size_t)ra1 * DIM + koff;

    // stage the X fragments once (8 x bf16x8 = 32 VGPRs)
    bf16x8 xa0[4], xa1[4];
#pragma unroll
    for (int kt = 0; kt < 4; ++kt) {
        int k0 = kt * 32;
        f32x4 lo0 = *(const f32x4*)(pa0f + k0), hi0 = *(const f32x4*)(pa0f + k0 + 4);
        f32x4 lo1 = *(const f32x4*)(pa1f + k0), hi1 = *(const f32x4*)(pa1f + k0 + 4);
#pragma unroll
        for (int j = 0; j < 4; ++j) {
            xa0[kt][j] = (short)f2bf(lo0[j]); xa0[kt][j + 4] = (short)f2bf(hi0[j]);
            xa1[kt][j] = (short)f2bf(lo1[j]); xa1[kt][j + 4] = (short)f2bf(hi1[j]);
        }
    }

#pragma unroll
    for (int w = 0; w < 3; ++w) {
        const unsigned short* W = (w == 0) ? Wq : (w == 1) ? Wk : Wv;
        const float* bias        = (w == 0) ? bq : (w == 1) ? bk : bv;
        unsigned short* out      = (w == 0) ? Q  : (w == 1) ? K  : V;

        f32x4 acc[2][8] = {};
        const unsigned short* pw = W + r16 * DIM + koff;
#pragma unroll
        for (int kt = 0; kt < 4; ++kt) {
            int k0 = kt * 32;
            bf16x8 bw[8];
#pragma unroll
            for (int ct = 0; ct < 8; ++ct)
                bw[ct] = *(const bf16x8*)(pw + ct * 16 * DIM + k0);
#pragma unroll
            for (int ct = 0; ct < 8; ++ct) {
                acc[0][ct] = __builtin_amdgcn_mfma_f32_16x16x32_bf16(xa0[kt], bw[ct], acc[0][ct], 0, 0, 0);
                acc[1][ct] = __builtin_amdgcn_mfma_f32_16x16x32_bf16(xa1[kt], bw[ct], acc[1][ct], 0, 0, 0);
            }
        }

        float biasv[8];
#pragma unroll
        for (int ct = 0; ct < 8; ++ct) biasv[ct] = bias[ct * 16 + r16];
#pragma unroll
        for (int rt = 0; rt < 2; ++rt) {
            int rbase = row0 + rt * 16 + kg * 4;
#pragma unroll
            for (int ct = 0; ct < 8; ++ct) {
                int c = ct * 16 + r16;
#pragma unroll
                for (int j = 0; j < 4; ++j) {
                    int r = rbase + j;
                    if (r < M) out[(size_t)r * DIM + c] = f2bf(acc[rt][ct][j] + biasv[ct]);
                }
            }
        }
    }
}

// ---------------- final GEMM: out = A@Wo^T + bo + res (fp32 out) ----------------
__global__ __launch_bounds__(256) void gemm_final(const unsigned short* __restrict__ A,
    const unsigned short* __restrict__ W, const float* __restrict__ bias,
    const float* __restrict__ res, float* __restrict__ out, int M)
{
    int lane = threadIdx.x & 63;
    int wave = threadIdx.x >> 6;
    int row0 = blockIdx.x * 128 + wave * 32;
    int r16 = lane & 15;
    int kg = lane >> 4;
    int koff = kg * 8;

    f32x4 acc[2][8] = {};
    int ra0 = row0 + r16;       if (ra0 > M - 1) ra0 = M - 1;
    int ra1 = row0 + 16 + r16;  if (ra1 > M - 1) ra1 = M - 1;
    const unsigned short* pa0 = A + (size_t)ra0 * DIM + koff;
    const unsigned short* pa1 = A + (size_t)ra1 * DIM + koff;
    const unsigned short* pw = W + r16 * DIM + koff;

#pragma unroll
    for (int k0 = 0; k0 < 128; k0 += 32) {
        bf16x8 a0 = *(const bf16x8*)(pa0 + k0);
        bf16x8 a1 = *(const bf16x8*)(pa1 + k0);
        bf16x8 bw[8];
#pragma unroll
        for (int ct = 0; ct < 8; ++ct)
            bw[ct] = *(const bf16x8*)(pw + ct * 16 * DIM + k0);
#pragma unroll
        for (int ct = 0; ct < 8; ++ct) {
            acc[0][ct] = __builtin_amdgcn_mfma_f32_16x16x32_bf16(a0, bw[ct], acc[0][ct], 0, 0, 0);
            acc[1][ct] = __builtin_amdgcn_mfma_f32_16x16x32_bf16(a1, bw[ct], acc[1][ct], 0, 0, 0);
        }
    }

    float biasv[8];
#pragma unroll
    for (int ct = 0; ct < 8; ++ct) biasv[ct] = bias[ct * 16 + r16];
#pragma unroll
    for (int rt = 0; rt < 2; ++rt) {
        int rbase = row0 + rt * 16 + kg * 4;
#pragma unroll
        for (int ct = 0; ct < 8; ++ct) {
            int c = ct * 16 + r16;
#pragma unroll
            for (int j = 0; j < 4; ++j) {
                int r = rbase + j;
                if (r < M)
                    out[(size_t)r * DIM + c] = acc[rt][ct][j] + biasv[ct] + res[(size_t)r * DIM + c];
            }
        }
    }
}

// ---------------- edge_index dtype detection (int64 vs int32) ----------------
__global__ void detect64(const int* __restrict__ e, int* __restrict__ flag, int E)
{
    __shared__ int nz;
    int t = threadIdx.x;
    if (t == 0) nz = 0;
    __syncthreads();
    int lim = (E < 4096) ? E : 4096;
    int mynz = 0;
    for (int i = 2 * t + 1; i < lim; i += 512) mynz |= (e[i] != 0);
    if (mynz) atomicOr(&nz, 1);
    __syncthreads();
    if (t == 0) *flag = nz ? 0 : 1;
}

__device__ __forceinline__ int load_idx(const int* p32, const long long* p64, int is64, int i)
{
    return is64 ? (int)p64[i] : p32[i];
}

// ---------------- CSR build ----------------
__global__ void hist_kernel(const int* __restrict__ row32, const long long* __restrict__ row64,
                            const int* __restrict__ flag, int* __restrict__ deg, int E)
{
    int e = blockIdx.x * blockDim.x + threadIdx.x;
    if (e < E) atomicAdd(&deg[load_idx(row32, row64, *flag, e)], 1);
}

__global__ __launch_bounds__(256) void scan1(const int* __restrict__ in, int* __restrict__ incl,
                                             int* __restrict__ bsums, int n)
{
    __shared__ int s[256];
    int t = threadIdx.x;
    int base = blockIdx.x * 1024 + t * 4;
    int v0 = (base + 0 < n) ? in[base + 0] : 0;
    int v1 = (base + 1 < n) ? in[base + 1] : 0;
    int v2 = (base + 2 < n) ? in[base + 2] : 0;
    int v3 = (base + 3 < n) ? in[base + 3] : 0;
    int sum = v0 + v1 + v2 + v3;
    s[t] = sum;
    __syncthreads();
    for (int off = 1; off < 256; off <<= 1) {
        int x = (t >= off) ? s[t - off] : 0;
        __syncthreads();
        s[t] += x;
        __syncthreads();
    }
    int excl = s[t] - sum;
    if (base + 0 < n) incl[base + 0] = excl + v0;
    if (base + 1 < n) incl[base + 1] = excl + v0 + v1;
    if (base + 2 < n) incl[base + 2] = excl + v0 + v1 + v2;
    if (base + 3 < n) incl[base + 3] = excl + sum;
    if (t == 255) bsums[blockIdx.x] = s[255];
}

// parallel exclusive scan of bsums (nb <= 512), one block of 256
__global__ __launch_bounds__(256) void scan2(int* bsums, int nb)
{
    __shared__ int s[512];
    int t = threadIdx.x;
    s[t] = (t < nb) ? bsums[t] : 0;
    s[t + 256] = (t + 256 < nb) ? bsums[t + 256] : 0;
    __syncthreads();
    for (int off = 1; off < 512; off <<= 1) {
        int x0 = (t >= off) ? s[t - off] : 0;
        int i1 = t + 256;
        int x1 = (i1 >= off) ? s[i1 - off] : 0;
        __syncthreads();
        s[t] += x0;
        s[i1] += x1;
        __syncthreads();
    }
    // exclusive from inclusive
    if (t < nb) bsums[t] = (t == 0) ? 0 : s[t - 1];
    if (t + 256 < nb) bsums[t + 256] = s[t + 255];
}

__global__ void scan3(const int* __restrict__ incl, const int* __restrict__ bofs,
                      int* __restrict__ rowptr, int n)
{
    int i = blockIdx.x * 256 + threadIdx.x;
    if (i == 0) rowptr[0] = 0;
    if (i < n) rowptr[i + 1] = incl[i] + bofs[i >> 10];
}

// cursor pre-initialized to rowptr[0..N-1]: pos = atomicAdd(&cursor[r],1) directly
__global__ void scatter_kernel(const int* __restrict__ e32, const long long* __restrict__ e64,
                               const int* __restrict__ flag,
                               int* __restrict__ cursor, int* __restrict__ colidx,
                               int* __restrict__ eidb, int E)
{
    int e = blockIdx.x * blockDim.x + threadIdx.x;
    if (e < E) {
        int is64 = *flag;
        int r = load_idx(e32, e64, is64, e);
        int c = load_idx(e32 + E, e64 + E, is64, e);
        int pos = atomicAdd(&cursor[r], 1);
        colidx[pos] = c;
        eidb[pos] = e;
    }
}

// ---------------- per-destination-node attention, one WAVE per node ----------------
// 256 thr = 4 waves = 4 nodes/block. lane l owns dims (2l, 2l+1); head h = l>>4.
// Wave-synchronous LDS (lgkmcnt fences, rule #18). Score/PV loops are 4-wide
// chunked: 4 independent row gathers in flight (validated round 7: 139->94us).
__global__ __launch_bounds__(256) void attn_kernel(const unsigned short* __restrict__ Q,
    const unsigned short* __restrict__ K, const unsigned short* __restrict__ V,
    const int* __restrict__ rowptr, const int* __restrict__ colidx,
    const int* __restrict__ eidb, unsigned short* __restrict__ attended,
    float* __restrict__ avg_out, int N)
{
    __shared__ float sc_s[4][CAP * 5];
    __shared__ int scol_s[4][CAP];
    __shared__ int sei_s[4][CAP];

    int wave = threadIdx.x >> 6;
    int l = threadIdx.x & 63;
    int n = blockIdx.x * 4 + wave;
    bool active = n < N;
    int h = l >> 4;       // head
    int hl = l & 15;      // lane within head group
    float* sc = sc_s[wave];
    int* scol = scol_s[wave];
    int* sei = sei_s[wave];

    int s0 = active ? rowptr[n] : 0;
    int deg = active ? (rowptr[n + 1] - s0) : 0;

    float q0 = 0.f, q1 = 0.f;
    if (active) {
        ushort2 qq = *(const ushort2*)(Q + (size_t)n * DIM + 2 * l);
        q0 = bf2f(qq.x); q1 = bf2f(qq.y);
    }

    if (deg <= CAP) {
        for (int e = l; e < deg; e += 64) { scol[e] = colidx[s0 + e]; sei[e] = eidb[s0 + e]; }
        wave_lds_fence();
        int e = 0;
        for (; e + 4 <= deg; e += 4) {
            int c0 = scol[e], c1 = scol[e + 1], c2 = scol[e + 2], c3 = scol[e + 3];
            ushort2 k0v = *(const ushort2*)(K + (size_t)c0 * DIM + 2 * l);
            ushort2 k1v = *(const ushort2*)(K + (size_t)c1 * DIM + 2 * l);
            ushort2 k2v = *(const ushort2*)(K + (size_t)c2 * DIM + 2 * l);
            ushort2 k3v = *(const ushort2*)(K + (size_t)c3 * DIM + 2 * l);
            float p0 = q0 * bf2f(k0v.x) + q1 * bf2f(k0v.y);
            float p1 = q0 * bf2f(k1v.x) + q1 * bf2f(k1v.y);
            float p2 = q0 * bf2f(k2v.x) + q1 * bf2f(k2v.y);
            float p3 = q0 * bf2f(k3v.x) + q1 * bf2f(k3v.y);
#pragma unroll
            for (int off = 8; off; off >>= 1) {
                p0 += __shfl_xor(p0, off); p1 += __shfl_xor(p1, off);
                p2 += __shfl_xor(p2, off); p3 += __shfl_xor(p3, off);
            }
            if (hl == 0) {
                sc[(e + 0) * 5 + h] = p0 * RSQRT_HD;
                sc[(e + 1) * 5 + h] = p1 * RSQRT_HD;
                sc[(e + 2) * 5 + h] = p2 * RSQRT_HD;
                sc[(e + 3) * 5 + h] = p3 * RSQRT_HD;
            }
        }
        for (; e < deg; ++e) {
            int c = scol[e];
            ushort2 kk = *(const ushort2*)(K + (size_t)c * DIM + 2 * l);
            float p = q0 * bf2f(kk.x) + q1 * bf2f(kk.y);
#pragma unroll
            for (int off = 8; off; off >>= 1) p += __shfl_xor(p, off);
            if (hl == 0) sc[e * 5 + h] = p * RSQRT_HD;
        }
        wave_lds_fence();
        float m = -INFINITY;
        for (int e2 = hl; e2 < deg; e2 += 16) m = fmaxf(m, sc[e2 * 5 + h]);
#pragma unroll
        for (int off = 8; off; off >>= 1) m = fmaxf(m, __shfl_xor(m, off));
        float ssum = 0.f;
        for (int e2 = hl; e2 < deg; e2 += 16) ssum += __expf(sc[e2 * 5 + h] - m);
#pragma unroll
        for (int off = 8; off; off >>= 1) ssum += __shfl_xor(ssum, off);
        float inv = 1.f / (ssum + 1e-16f);
        for (int e2 = hl; e2 < deg; e2 += 16) sc[e2 * 5 + h] = __expf(sc[e2 * 5 + h] - m) * inv;
        wave_lds_fence();
        for (int e2 = l; e2 < deg; e2 += 64)
            avg_out[sei[e2]] = 0.25f * (sc[e2 * 5] + sc[e2 * 5 + 1] + sc[e2 * 5 + 2] + sc[e2 * 5 + 3]);
        float a0 = 0.f, a1 = 0.f;
        int e3 = 0;
        for (; e3 + 4 <= deg; e3 += 4) {
            int c0 = scol[e3], c1 = scol[e3 + 1], c2 = scol[e3 + 2], c3 = scol[e3 + 3];
            float w0 = sc[(e3 + 0) * 5 + h];
            float w1 = sc[(e3 + 1) * 5 + h];
            float w2 = sc[(e3 + 2) * 5 + h];
            float w3 = sc[(e3 + 3) * 5 + h];
            ushort2 v0 = *(const ushort2*)(V + (size_t)c0 * DIM + 2 * l);
            ushort2 v1 = *(const ushort2*)(V + (size_t)c1 * DIM + 2 * l);
            ushort2 v2 = *(const ushort2*)(V + (size_t)c2 * DIM + 2 * l);
            ushort2 v3 = *(const ushort2*)(V + (size_t)c3 * DIM + 2 * l);
            a0 += w0 * bf2f(v0.x); a1 += w0 * bf2f(v0.y);
            a0 += w1 * bf2f(v1.x); a1 += w1 * bf2f(v1.y);
            a0 += w2 * bf2f(v2.x); a1 += w2 * bf2f(v2.y);
            a0 += w3 * bf2f(v3.x); a1 += w3 * bf2f(v3.y);
        }
        for (; e3 < deg; ++e3) {
            float a = sc[e3 * 5 + h];
            ushort2 vv = *(const ushort2*)(V + (size_t)scol[e3] * DIM + 2 * l);
            a0 += a * bf2f(vv.x);
            a1 += a * bf2f(vv.y);
        }
        if (active) {
            ushort2 o; o.x = f2bf(a0); o.y = f2bf(a1);
            *(ushort2*)(attended + (size_t)n * DIM + 2 * l) = o;
        }
    } else {
        // streaming two-pass fallback (deg > CAP; correct for any degree)
        float m = -INFINITY, ssum = 0.f;
        for (int e = 0; e < deg; ++e) {
            int c = colidx[s0 + e];
            ushort2 kk = *(const ushort2*)(K + (size_t)c * DIM + 2 * l);
            float p = q0 * bf2f(kk.x) + q1 * bf2f(kk.y);
#pragma unroll
            for (int off = 8; off; off >>= 1) p += __shfl_xor(p, off);
            p *= RSQRT_HD;
            float mn = fmaxf(m, p);
            ssum = ssum * __expf(m - mn) + __expf(p - mn);
            m = mn;
        }
        float inv = 1.f / (ssum + 1e-16f);
        float a0 = 0.f, a1 = 0.f;
        for (int e = 0; e < deg; ++e) {
            int c = colidx[s0 + e];
            ushort2 kk = *(const ushort2*)(K + (size_t)c * DIM + 2 * l);
            float p = q0 * bf2f(kk.x) + q1 * bf2f(kk.y);
#pragma unroll
            for (int off = 8; off; off >>= 1) p += __shfl_xor(p, off);
            float a = __expf(p * RSQRT_HD - m) * inv;
            float asum = a + __shfl_xor(a, 16);
            asum += __shfl_xor(asum, 32);
            if (l == 0) avg_out[eidb[s0 + e]] = 0.25f * asum;
            ushort2 vv = *(const ushort2*)(V + (size_t)c * DIM + 2 * l);
            a0 += a * bf2f(vv.x);
            a1 += a * bf2f(vv.y);
        }
        if (active) {
            ushort2 o; o.x = f2bf(a0); o.y = f2bf(a1);
            *(ushort2*)(attended + (size_t)n * DIM + 2 * l) = o;
        }
    }
}

extern "C" void kernel_launch(void* const* d_in, const int* in_sizes, int n_in,
                              void* d_out, int out_size, void* d_ws, size_t ws_size,
                              hipStream_t stream)
{
    const float* x  = (const float*)d_in[0];
    const int* e32  = (const int*)d_in[1];
    const long long* e64 = (const long long*)d_in[1];
    const float* Wq = (const float*)d_in[2];
    const float* bq = (const float*)d_in[3];
    const float* Wk = (const float*)d_in[4];
    const float* bk = (const float*)d_in[5];
    const float* Wv = (const float*)d_in[6];
    const float* bv = (const float*)d_in[7];
    const float* Wo = (const float*)d_in[8];
    const float* bo = (const float*)d_in[9];

    int N = in_sizes[0] / DIM;
    int E = in_sizes[1] / 2;

    float* out = (float*)d_out;
    float* avg_out = out + (size_t)N * DIM;

    char* w = (char*)d_ws;
    auto carve = [&](size_t bytes) -> void* {
        void* p = (void*)w;
        w += (bytes + 255) & ~(size_t)255;
        return p;
    };
    unsigned short* Qb = (unsigned short*)carve((size_t)N * DIM * 2);  // reused as `attended`
    unsigned short* Kb = (unsigned short*)carve((size_t)N * DIM * 2);
    unsigned short* Vb = (unsigned short*)carve((size_t)N * DIM * 2);
    unsigned short* Wqb = (unsigned short*)carve(DIM * DIM * 2);
    unsigned short* Wkb = (unsigned short*)carve(DIM * DIM * 2);
    unsigned short* Wvb = (unsigned short*)carve(DIM * DIM * 2);
    unsigned short* Wob = (unsigned short*)carve(DIM * DIM * 2);
    int* deg    = (int*)carve((size_t)N * 4);
    int* tmp    = (int*)carve((size_t)N * 4);
    int* rowptr = (int*)carve(((size_t)N + 1) * 4);
    int* cursor = (int*)carve((size_t)N * 4);
    int* bsums  = (int*)carve(512 * 4);
    int* flag   = (int*)carve(256);
    int* colidx = (int*)carve((size_t)E * 4);
    int* eidb   = (int*)carve((size_t)E * 4);

    hipMemsetAsync(deg, 0, (size_t)N * 4, stream);

    cast_w4<<<dim3(8, 4), 256, 0, stream>>>(Wq, Wk, Wv, Wo, Wqb, Wkb, Wvb, Wob);

    detect64<<<1, 256, 0, stream>>>(e32, flag, 2 * E);
    hist_kernel<<<(E + 255) / 256, 256, 0, stream>>>(e32, e64, flag, deg, E);
    int nb = (N + 1023) / 1024;
    scan1<<<nb, 256, 0, stream>>>(deg, tmp, bsums, N);
    scan2<<<1, 256, 0, stream>>>(bsums, nb);
    scan3<<<(N + 255) / 256, 256, 0, stream>>>(tmp, bsums, rowptr, N);
    // cursor <- rowptr starts, then scatter atomically bumps cursor directly
    hipMemcpyAsync(cursor, rowptr, (size_t)N * 4, hipMemcpyDeviceToDevice, stream);
    scatter_kernel<<<(E + 255) / 256, 256, 0, stream>>>(e32, e64, flag, cursor, colidx, eidb, E);

    int gx = (N + 127) / 128;
    gemm_qkv_fused<<<gx, 256, 0, stream>>>(x, Wqb, Wkb, Wvb, bq, bk, bv, Qb, Kb, Vb, N);

    attn_kernel<<<(N + 3) / 4, 256, 0, stream>>>(Qb, Kb, Vb, rowptr, colidx, eidb,
                                                 Qb /*attended aliases Q*/, avg_out, N);

    gemm_final<<<gx, 256, 0, stream>>>(Qb, Wob, bo, x, out, N);
}